// Round 1
// 411.757 us; speedup vs baseline: 1.1903x; 1.1903x over previous
//
#include <hip/hip_runtime.h>

typedef short bf16x8 __attribute__((ext_vector_type(8)));
typedef float f32x4 __attribute__((ext_vector_type(4)));

__device__ __forceinline__ float b2f(unsigned short u) {
  union { unsigned int i; float f; } v; v.i = ((unsigned int)u) << 16; return v.f;
}
__device__ __forceinline__ unsigned short f2b(float f) {
  unsigned int u = __float_as_uint(f);
  u += 0x7fffu + ((u >> 16) & 1u);
  return (unsigned short)(u >> 16);
}
__device__ __forceinline__ float silu_f(float s) { return s / (1.0f + __expf(-s)); }

// split fp32 -> (hi, lo) bf16
__device__ __forceinline__ void split2(float f, unsigned short& h, unsigned short& l) {
  h = f2b(f);
  l = f2b(f - b2f(h));
}

// async 16B/lane global->LDS. LDS dest = wave-uniform base + lane*16 (linear).
__device__ __forceinline__ void gload16(const unsigned short* g, unsigned short* l) {
  __builtin_amdgcn_global_load_lds(
      (const __attribute__((address_space(1))) unsigned int*)g,
      (__attribute__((address_space(3))) unsigned int*)l, 16, 0, 0);
}

// unpack 8 packed (hi | lo<<16) u32 -> hi/lo bf16x8 via v_perm (2 ops per pair)
__device__ __forceinline__ void unpack8(const unsigned* p, bf16x8& hi, bf16x8& lo) {
  uint4 a = *(const uint4*)p;
  uint4 b = *(const uint4*)(p + 4);
  unsigned u[8] = {a.x, a.y, a.z, a.w, b.x, b.y, b.z, b.w};
  unsigned hw[4], lw[4];
  #pragma unroll
  for (int j = 0; j < 4; j++) {
    hw[j] = __builtin_amdgcn_perm(u[2 * j + 1], u[2 * j], 0x05040100u);
    lw[j] = __builtin_amdgcn_perm(u[2 * j + 1], u[2 * j], 0x07060302u);
  }
  hi = *(bf16x8*)hw;
  lo = *(bf16x8*)lw;
}

// K0: split W fp32 -> Wh/Wl bf16 planes [768][256], once.
__global__ __launch_bounds__(256) void k_wsplit(
    const float* __restrict__ W, unsigned short* __restrict__ Wh,
    unsigned short* __restrict__ Wl) {
  int e = (blockIdx.x * 256 + threadIdx.x) * 8;  // 96 blocks * 256 * 8 = 768*256
  float4 a = *(const float4*)(W + e);
  float4 b = *(const float4*)(W + e + 4);
  float v[8] = {a.x, a.y, a.z, a.w, b.x, b.y, b.z, b.w};
  unsigned short h[8], l[8];
  #pragma unroll
  for (int j = 0; j < 8; j++) split2(v[j], h[j], l[j]);
  uint4 ph, pl;
  ph.x = h[0] | ((unsigned)h[1] << 16); ph.y = h[2] | ((unsigned)h[3] << 16);
  ph.z = h[4] | ((unsigned)h[5] << 16); ph.w = h[6] | ((unsigned)h[7] << 16);
  pl.x = l[0] | ((unsigned)l[1] << 16); pl.y = l[2] | ((unsigned)l[3] << 16);
  pl.z = l[4] | ((unsigned)l[5] << 16); pl.w = l[6] | ((unsigned)l[7] << 16);
  *(uint4*)(Wh + e) = ph;
  *(uint4*)(Wl + e) = pl;
}

// K1: T = silu(x + pab) + pqb, written TRANSPOSED as split planes into out[:,256:512]:
//   per batch: Th u16[4096][256] then Tl u16[4096][256] (2MB + 2MB = exactly the region).
__global__ __launch_bounds__(256) void k_prep(
    const float* __restrict__ x, const float* __restrict__ pab,
    const float* __restrict__ pqb, float* __restrict__ out) {
  __shared__ unsigned short th[64 * 64], tl[64 * 64];  // [n][c], sub-chunk swizzled
  int blk = blockIdx.x;
  int nb = blk & 63;
  int cb = (blk >> 6) & 3;
  int b = blk >> 8;
  int n0 = nb * 64, c0 = cb * 64;
  int t = threadIdx.x;
  int nn = (t & 15) * 4;
  #pragma unroll
  for (int p = 0; p < 2; p++) {
    int c = 2 * (p * 16 + (t >> 4));  // even
    float pa0 = pab[c0 + c], pq0 = pqb[c0 + c];
    float pa1 = pab[c0 + c + 1], pq1 = pqb[c0 + c + 1];
    float4 x0 = *(const float4*)(x + ((long long)(b * 256 + c0 + c)) * 4096 + n0 + nn);
    float4 x1 = *(const float4*)(x + ((long long)(b * 256 + c0 + c + 1)) * 4096 + n0 + nn);
    float t0[4] = {silu_f(x0.x + pa0) + pq0, silu_f(x0.y + pa0) + pq0,
                   silu_f(x0.z + pa0) + pq0, silu_f(x0.w + pa0) + pq0};
    float t1[4] = {silu_f(x1.x + pa1) + pq1, silu_f(x1.y + pa1) + pq1,
                   silu_f(x1.z + pa1) + pq1, silu_f(x1.w + pa1) + pq1};
    #pragma unroll
    for (int j = 0; j < 4; j++) {
      int nr = nn + j;
      unsigned short h0, l0, h1, l1;
      split2(t0[j], h0, l0);
      split2(t1[j], h1, l1);
      // physical col: swizzle 8-elem sub-chunk by row (c even => pair stays in chunk)
      int pcol = ((((c >> 3) ^ (nr & 7)) << 3) | (c & 7));
      *(unsigned int*)(th + nr * 64 + pcol) = (unsigned)h0 | ((unsigned)h1 << 16);
      *(unsigned int*)(tl + nr * 64 + pcol) = (unsigned)l0 | ((unsigned)l1 << 16);
    }
  }
  __syncthreads();
  unsigned short* Th = (unsigned short*)(out + ((long long)(b * 512 + 256)) * 4096);
  unsigned short* Tl = Th + 4096 * 256;
  #pragma unroll
  for (int q = 0; q < 2; q++) {
    int s = q * 256 + t;
    int n = s >> 3, sc = s & 7;
    int psc = sc ^ (n & 7);
    uint4 vh = *(const uint4*)(th + n * 64 + psc * 8);
    uint4 vl = *(const uint4*)(tl + n * 64 + psc * 8);
    *(uint4*)(Th + (long long)(n0 + n) * 256 + c0 + sc * 8) = vh;
    *(uint4*)(Tl + (long long)(n0 + n) * 256 + c0 + sc * 8) = vl;
  }
}

// K6 (last): x_preact = silu(x + pab) fp32 -> out[:,0:256]
__global__ __launch_bounds__(256) void k_act(
    const float* __restrict__ x, const float* __restrict__ pab,
    float* __restrict__ out) {
  long long e = ((long long)blockIdx.x * 256 + threadIdx.x) * 4;
  int b = (int)(e >> 20);
  int c = ((int)(e >> 12)) & 255;
  int n = (int)(e & 4095);
  float4 xv = *(const float4*)(x + e);
  float pa = pab[c];
  float4 o = {silu_f(xv.x + pa), silu_f(xv.y + pa), silu_f(xv.z + pa), silu_f(xv.w + pa)};
  *(float4*)(out + ((long long)(b * 512 + c)) * 4096 + n) = o;
}

// K2/K4: GEMM qkv rows [o_base, o_base+obt*128). USE_LO=1 -> 3-term split-bf16.
// Pure gload_lds staging from pre-split planes; XOR-swizzled (source-side + read-side).
//   part 0 (q): +bias+PE, FiLM -> out[:,0:256] packed (hi|lo<<16) u32
//   part 1 (k): +bias+PE      -> kv packed u32
//   part 2 (v): +bias         -> kv fp32
template <int USE_LO>
__global__ __launch_bounds__(256) void k_qkv(
    const unsigned short* __restrict__ Wh, const unsigned short* __restrict__ Wl,
    const float* __restrict__ qkvb,
    const float* __restrict__ peqh, const float* __restrict__ peqw,
    const float* __restrict__ pekh, const float* __restrict__ pekw,
    const float* __restrict__ modm, const float* __restrict__ modb,
    float* __restrict__ out, float* __restrict__ kv,
    int o_base, int obt) {
  extern __shared__ unsigned short sm[];
  unsigned short* Ah = sm;                            // [128][64]
  unsigned short* Al = sm + 8192;                     // USE_LO only
  unsigned short* Bh = sm + (USE_LO ? 16384 : 8192);  // [128][64]
  unsigned short* Bl = sm + 24576;                    // USE_LO only

  int bx = blockIdx.x;
  int nb = bx & 31;
  int hb = bx >> 5;
  int ob = hb % obt;
  int b = hb / obt;
  int o0 = o_base + ob * 128, n0 = nb * 128;
  int t = threadIdx.x;
  int lane = t & 63, w = t >> 6;
  int wm = w >> 1, wn = w & 1;
  int l15 = lane & 15, l4 = lane >> 4;
  int sx = l15 & 7;

  const unsigned short* Th =
      (const unsigned short*)(out + ((long long)(b * 512 + 256)) * 4096);
  const unsigned short* Tl = Th + 4096 * 256;

  // per-wave staging plane assignment
  const unsigned short* src;
  unsigned short* dst;
  int row0;
  if (USE_LO) {
    if (w == 0)      { src = Wh; dst = Ah; row0 = o0; }
    else if (w == 1) { src = Wl; dst = Al; row0 = o0; }
    else if (w == 2) { src = Th; dst = Bh; row0 = n0; }
    else             { src = Tl; dst = Bl; row0 = n0; }
  } else {
    if (w == 0)      { src = Wh; dst = Ah;        row0 = o0; }
    else if (w == 1) { src = Wh; dst = Ah + 4096; row0 = o0 + 64; }
    else if (w == 2) { src = Th; dst = Bh;        row0 = n0; }
    else             { src = Th; dst = Bh + 4096; row0 = n0 + 64; }
  }
  const int nI = USE_LO ? 16 : 8;  // 8 rows per gload16 instruction
  int lr = lane >> 3;
  // source-side swizzle: lane chunk (lane&7) fetches data chunk (lane&7)^lr
  int laneoff = lr * 256 + (((lane & 7) ^ lr) << 3);
  const unsigned short* sbase = src + (long long)row0 * 256 + laneoff;

  f32x4 z = {0.f, 0.f, 0.f, 0.f};
  f32x4 acc[4][4];
  #pragma unroll
  for (int i = 0; i < 4; i++)
    #pragma unroll
    for (int j = 0; j < 4; j++) acc[i][j] = z;

  for (int k0 = 0; k0 < 256; k0 += 64) {
    const unsigned short* sp = sbase + k0;
    #pragma unroll
    for (int i = 0; i < nI; i++) gload16(sp + i * 2048, dst + i * 512);
    __syncthreads();
    #pragma unroll
    for (int ks = 0; ks < 2; ks++) {
      bf16x8 ah[4], bh[4], al[4], bl[4];
      int sw = (((ks * 4 + l4) ^ sx) << 3);  // read-side swizzle (row&7 == sx)
      #pragma unroll
      for (int i = 0; i < 4; i++) {
        int rowA = (wm * 64 + i * 16 + l15) * 64;
        int rowB = (wn * 64 + i * 16 + l15) * 64;
        ah[i] = *(const bf16x8*)(Ah + rowA + sw);
        bh[i] = *(const bf16x8*)(Bh + rowB + sw);
        if (USE_LO) {
          al[i] = *(const bf16x8*)(Al + rowA + sw);
          bl[i] = *(const bf16x8*)(Bl + rowB + sw);
        }
      }
      #pragma unroll
      for (int i = 0; i < 4; i++)
        #pragma unroll
        for (int j = 0; j < 4; j++) {
          acc[i][j] = __builtin_amdgcn_mfma_f32_16x16x32_bf16(ah[i], bh[j], acc[i][j], 0, 0, 0);
          if (USE_LO) {
            acc[i][j] = __builtin_amdgcn_mfma_f32_16x16x32_bf16(ah[i], bl[j], acc[i][j], 0, 0, 0);
            acc[i][j] = __builtin_amdgcn_mfma_f32_16x16x32_bf16(al[i], bh[j], acc[i][j], 0, 0, 0);
          }
        }
    }
    __syncthreads();
  }

  int part = o0 >> 8;
  #pragma unroll
  for (int i = 0; i < 4; i++) {
    #pragma unroll
    for (int r = 0; r < 4; r++) {
      int o = o0 + wm * 64 + i * 16 + l4 * 4 + r;
      int cch = o & 255;
      float bias = qkvb[o];
      float mm = 0.f, mb = 0.f;
      if (part == 0) { mm = modm[b * 256 + cch]; mb = modb[b * 256 + cch]; }
      #pragma unroll
      for (int j = 0; j < 4; j++) {
        int n = n0 + wn * 64 + j * 16 + l15;
        float v = acc[i][j][r] + bias;
        int hh = n >> 6, ww = n & 63;
        if (part == 0) {
          v += peqh[cch * 64 + hh] + peqw[cch * 64 + ww];
          v = v * mm + mb;
          unsigned short h, l; split2(v, h, l);
          ((unsigned*)out)[((long long)(b * 512 + cch)) * 4096 + n] =
              (unsigned)h | ((unsigned)l << 16);
        } else if (part == 1) {
          v += pekh[cch * 64 + hh] + pekw[cch * 64 + ww];
          unsigned short h, l; split2(v, h, l);
          ((unsigned*)kv)[((long long)(b * 256 + cch)) * 4096 + n] =
              (unsigned)h | ((unsigned)l << 16);
        } else {
          kv[((long long)(b * 256 + cch)) * 4096 + n] = v;
        }
      }
    }
  }
}

// K3: logitsP[chunk][b,h,c,d] = scale * sum_{n in chunk} q[c,n] k[d,n]
// q, k read as packed split-bf16 (written by k_qkv) -> v_perm unpack, no cvt.
__global__ __launch_bounds__(256) void k_logits(
    const unsigned* __restrict__ qp, const unsigned* __restrict__ kp,
    float* __restrict__ logitsP) {
  int bx = blockIdx.x;
  int chunk = bx & 3, bh = bx >> 2;
  int b = bh >> 3, h = bh & 7;
  int t = threadIdx.x, lane = t & 63, w = t >> 6;
  int l15 = lane & 15, l4 = lane >> 4;
  const unsigned* qb = qp + ((long long)(b * 512 + h * 32)) * 4096;
  const unsigned* kb = kp + ((long long)(b * 256 + h * 32)) * 4096;
  f32x4 z = {0.f, 0.f, 0.f, 0.f};
  f32x4 acc[2][2] = {z, z, z, z};
  int nstep0 = chunk * 1024 + w * 256;
  for (int it = 0; it < 8; it++) {
    int n = nstep0 + it * 32 + l4 * 8;
    bf16x8 qh0, ql0, qh1, ql1, kh0, kl0, kh1, kl1;
    unpack8(qb + (long long)l15 * 4096 + n, qh0, ql0);
    unpack8(qb + (long long)(16 + l15) * 4096 + n, qh1, ql1);
    unpack8(kb + (long long)l15 * 4096 + n, kh0, kl0);
    unpack8(kb + (long long)(16 + l15) * 4096 + n, kh1, kl1);
    acc[0][0] = __builtin_amdgcn_mfma_f32_16x16x32_bf16(qh0, kh0, acc[0][0], 0, 0, 0);
    acc[0][0] = __builtin_amdgcn_mfma_f32_16x16x32_bf16(qh0, kl0, acc[0][0], 0, 0, 0);
    acc[0][0] = __builtin_amdgcn_mfma_f32_16x16x32_bf16(ql0, kh0, acc[0][0], 0, 0, 0);
    acc[0][1] = __builtin_amdgcn_mfma_f32_16x16x32_bf16(qh0, kh1, acc[0][1], 0, 0, 0);
    acc[0][1] = __builtin_amdgcn_mfma_f32_16x16x32_bf16(qh0, kl1, acc[0][1], 0, 0, 0);
    acc[0][1] = __builtin_amdgcn_mfma_f32_16x16x32_bf16(ql0, kh1, acc[0][1], 0, 0, 0);
    acc[1][0] = __builtin_amdgcn_mfma_f32_16x16x32_bf16(qh1, kh0, acc[1][0], 0, 0, 0);
    acc[1][0] = __builtin_amdgcn_mfma_f32_16x16x32_bf16(qh1, kl0, acc[1][0], 0, 0, 0);
    acc[1][0] = __builtin_amdgcn_mfma_f32_16x16x32_bf16(ql1, kh0, acc[1][0], 0, 0, 0);
    acc[1][1] = __builtin_amdgcn_mfma_f32_16x16x32_bf16(qh1, kh1, acc[1][1], 0, 0, 0);
    acc[1][1] = __builtin_amdgcn_mfma_f32_16x16x32_bf16(qh1, kl1, acc[1][1], 0, 0, 0);
    acc[1][1] = __builtin_amdgcn_mfma_f32_16x16x32_bf16(ql1, kh1, acc[1][1], 0, 0, 0);
  }
  __shared__ float red[4][1024];
  #pragma unroll
  for (int ch = 0; ch < 2; ch++)
    #pragma unroll
    for (int dh = 0; dh < 2; dh++)
      #pragma unroll
      for (int r = 0; r < 4; r++) {
        int crow = ch * 16 + l4 * 4 + r;
        int dcol = dh * 16 + l15;
        red[w][crow * 32 + dcol] = acc[ch][dh][r];
      }
  __syncthreads();
  const float scale = 0.1767766952966369f;  // 1/sqrt(32)
  #pragma unroll
  for (int i = 0; i < 4; i++) {
    int idx = i * 256 + t;
    float s = (red[0][idx] + red[1][idx] + red[2][idx] + red[3][idx]) * scale;
    logitsP[(long long)chunk * 131072 + bh * 1024 + idx] = s;
  }
}

// K5: softmax (sum 4 partials) + out = weights @ v -> out[:,256:512] fp32
__global__ __launch_bounds__(256) void k_pv(
    const float* __restrict__ kv,    // v
    const float* __restrict__ logitsP,
    float* __restrict__ out) {
  int bx = blockIdx.x;
  int ntile = bx & 15, bh = bx >> 4;
  int b = bh >> 3, h = bh & 7;
  int t = threadIdx.x;
  __shared__ float raw[1024];
  __shared__ float wsm[32][33];
  #pragma unroll
  for (int i = 0; i < 4; i++) {
    int idx = i * 256 + t;
    raw[idx] = logitsP[bh * 1024 + idx] + logitsP[131072 + bh * 1024 + idx]
             + logitsP[262144 + bh * 1024 + idx] + logitsP[393216 + bh * 1024 + idx];
  }
  __syncthreads();
  if (t < 32) {
    float mx = -1e30f;
    for (int d = 0; d < 32; d++) mx = fmaxf(mx, raw[t * 32 + d]);
    float e[32]; float s = 0.f;
    for (int d = 0; d < 32; d++) { e[d] = __expf(raw[t * 32 + d] - mx); s += e[d]; }
    float inv = 1.0f / s;
    for (int d = 0; d < 32; d++) wsm[t][d] = e[d] * inv;
  }
  __syncthreads();
  int rg = t >> 6;          // wave-uniform -> wsm broadcast
  int nl = (t & 63) * 4;
  int n0 = ntile * 256 + nl;
  const float* vb = kv + ((long long)(b * 256 + h * 32)) * 4096 + n0;
  float acc[8][4];
  #pragma unroll
  for (int r = 0; r < 8; r++)
    #pragma unroll
    for (int i = 0; i < 4; i++) acc[r][i] = 0.f;
  for (int d = 0; d < 32; d++) {
    float4 vv = *(const float4*)(vb + (long long)d * 4096);
    #pragma unroll
    for (int r = 0; r < 8; r++) {
      float wv = wsm[rg * 8 + r][d];
      acc[r][0] += wv * vv.x; acc[r][1] += wv * vv.y;
      acc[r][2] += wv * vv.z; acc[r][3] += wv * vv.w;
    }
  }
  #pragma unroll
  for (int r = 0; r < 8; r++) {
    long long oidx = ((long long)(b * 512 + 256 + h * 32 + rg * 8 + r)) * 4096 + n0;
    float4 ov = {acc[r][0], acc[r][1], acc[r][2], acc[r][3]};
    *(float4*)(out + oidx) = ov;
  }
}

extern "C" void kernel_launch(void* const* d_in, const int* in_sizes, int n_in,
                              void* d_out, int out_size, void* d_ws, size_t ws_size,
                              hipStream_t stream) {
  const float* x    = (const float*)d_in[0];
  const float* modm = (const float*)d_in[1];
  const float* modb = (const float*)d_in[2];
  const float* Wq   = (const float*)d_in[3];
  const float* qkvb = (const float*)d_in[4];
  const float* peqh = (const float*)d_in[5];
  const float* peqw = (const float*)d_in[6];
  const float* pekh = (const float*)d_in[7];
  const float* pekw = (const float*)d_in[8];
  const float* pab  = (const float*)d_in[9];
  const float* pqb  = (const float*)d_in[10];
  float* out = (float*)d_out;

  // ws layout (67 MB total, <= 69.2 MB proven):
  //   [0, 0.75MB)  Wh/Wl u16[768][256] split-bf16 planes
  //   [1MB, 3MB)   logitsP f32[4][128][1024]
  //   [3MB, 67MB)  kv: k packed u32 [16][256][4096], then v fp32 (same region)
  unsigned short* Wh = (unsigned short*)d_ws;
  unsigned short* Wl = Wh + 768 * 256;
  float* logitsP = (float*)((char*)d_ws + (1 << 20));
  float* kv = (float*)((char*)d_ws + 3 * (1 << 20));

  k_wsplit<<<96, 256, 0, stream>>>(Wq, Wh, Wl);
  k_prep<<<4096, 256, 0, stream>>>(x, pab, pqb, out);
  k_qkv<1><<<2048, 256, 65536, stream>>>(Wh, Wl, qkvb, peqh, peqw, pekh, pekw,
                                         modm, modb, out, kv, 0, 4);
  k_logits<<<512, 256, 0, stream>>>((const unsigned*)out, (const unsigned*)kv, logitsP);
  k_qkv<0><<<1024, 256, 32768, stream>>>(Wh, Wl, qkvb, peqh, peqw, pekh, pekw,
                                         modm, modb, out, kv, 512, 2);
  k_pv<<<2048, 256, 0, stream>>>(kv, logitsP, out);
  k_act<<<16384, 256, 0, stream>>>(x, pab, out);
}

// Round 2
// 408.728 us; speedup vs baseline: 1.1991x; 1.0074x over previous
//
#include <hip/hip_runtime.h>

typedef short bf16x8 __attribute__((ext_vector_type(8)));
typedef float f32x4 __attribute__((ext_vector_type(4)));

__device__ __forceinline__ float b2f(unsigned short u) {
  union { unsigned int i; float f; } v; v.i = ((unsigned int)u) << 16; return v.f;
}
__device__ __forceinline__ unsigned short f2b(float f) {
  unsigned int u = __float_as_uint(f);
  u += 0x7fffu + ((u >> 16) & 1u);
  return (unsigned short)(u >> 16);
}
__device__ __forceinline__ float silu_f(float s) { return s / (1.0f + __expf(-s)); }

// split fp32 -> (hi, lo) bf16
__device__ __forceinline__ void split2(float f, unsigned short& h, unsigned short& l) {
  h = f2b(f);
  l = f2b(f - b2f(h));
}

// async 16B/lane global->LDS. LDS dest = wave-uniform base + lane*16 (linear).
__device__ __forceinline__ void gload16(const unsigned short* g, unsigned short* l) {
  __builtin_amdgcn_global_load_lds(
      (const __attribute__((address_space(1))) unsigned int*)g,
      (__attribute__((address_space(3))) unsigned int*)l, 16, 0, 0);
}

// unpack 8 packed (hi | lo<<16) u32 -> hi/lo bf16x8 via v_perm (2 ops per pair)
__device__ __forceinline__ void unpack8(const unsigned* p, bf16x8& hi, bf16x8& lo) {
  uint4 a = *(const uint4*)p;
  uint4 b = *(const uint4*)(p + 4);
  unsigned u[8] = {a.x, a.y, a.z, a.w, b.x, b.y, b.z, b.w};
  unsigned hw[4], lw[4];
  #pragma unroll
  for (int j = 0; j < 4; j++) {
    hw[j] = __builtin_amdgcn_perm(u[2 * j + 1], u[2 * j], 0x05040100u);
    lw[j] = __builtin_amdgcn_perm(u[2 * j + 1], u[2 * j], 0x07060302u);
  }
  hi = *(bf16x8*)hw;
  lo = *(bf16x8*)lw;
}

// K0: split W fp32 -> Wh/Wl bf16 planes [768][256], once.
__global__ __launch_bounds__(256) void k_wsplit(
    const float* __restrict__ W, unsigned short* __restrict__ Wh,
    unsigned short* __restrict__ Wl) {
  int e = (blockIdx.x * 256 + threadIdx.x) * 8;  // 96 blocks * 256 * 8 = 768*256
  float4 a = *(const float4*)(W + e);
  float4 b = *(const float4*)(W + e + 4);
  float v[8] = {a.x, a.y, a.z, a.w, b.x, b.y, b.z, b.w};
  unsigned short h[8], l[8];
  #pragma unroll
  for (int j = 0; j < 8; j++) split2(v[j], h[j], l[j]);
  uint4 ph, pl;
  ph.x = h[0] | ((unsigned)h[1] << 16); ph.y = h[2] | ((unsigned)h[3] << 16);
  ph.z = h[4] | ((unsigned)h[5] << 16); ph.w = h[6] | ((unsigned)h[7] << 16);
  pl.x = l[0] | ((unsigned)l[1] << 16); pl.y = l[2] | ((unsigned)l[3] << 16);
  pl.z = l[4] | ((unsigned)l[5] << 16); pl.w = l[6] | ((unsigned)l[7] << 16);
  *(uint4*)(Wh + e) = ph;
  *(uint4*)(Wl + e) = pl;
}

// K1: T = silu(x + pab) + pqb, written TRANSPOSED as split planes into out[:,256:512]:
//   per batch: Th u16[4096][256] then Tl u16[4096][256] (2MB + 2MB = exactly the region).
__global__ __launch_bounds__(256) void k_prep(
    const float* __restrict__ x, const float* __restrict__ pab,
    const float* __restrict__ pqb, float* __restrict__ out) {
  __shared__ unsigned short th[64 * 64], tl[64 * 64];  // [n][c], sub-chunk swizzled
  int blk = blockIdx.x;
  int nb = blk & 63;
  int cb = (blk >> 6) & 3;
  int b = blk >> 8;
  int n0 = nb * 64, c0 = cb * 64;
  int t = threadIdx.x;
  int nn = (t & 15) * 4;
  #pragma unroll
  for (int p = 0; p < 2; p++) {
    int c = 2 * (p * 16 + (t >> 4));  // even
    float pa0 = pab[c0 + c], pq0 = pqb[c0 + c];
    float pa1 = pab[c0 + c + 1], pq1 = pqb[c0 + c + 1];
    float4 x0 = *(const float4*)(x + ((long long)(b * 256 + c0 + c)) * 4096 + n0 + nn);
    float4 x1 = *(const float4*)(x + ((long long)(b * 256 + c0 + c + 1)) * 4096 + n0 + nn);
    float t0[4] = {silu_f(x0.x + pa0) + pq0, silu_f(x0.y + pa0) + pq0,
                   silu_f(x0.z + pa0) + pq0, silu_f(x0.w + pa0) + pq0};
    float t1[4] = {silu_f(x1.x + pa1) + pq1, silu_f(x1.y + pa1) + pq1,
                   silu_f(x1.z + pa1) + pq1, silu_f(x1.w + pa1) + pq1};
    #pragma unroll
    for (int j = 0; j < 4; j++) {
      int nr = nn + j;
      unsigned short h0, l0, h1, l1;
      split2(t0[j], h0, l0);
      split2(t1[j], h1, l1);
      // physical col: swizzle 8-elem sub-chunk by row (c even => pair stays in chunk)
      int pcol = ((((c >> 3) ^ (nr & 7)) << 3) | (c & 7));
      *(unsigned int*)(th + nr * 64 + pcol) = (unsigned)h0 | ((unsigned)h1 << 16);
      *(unsigned int*)(tl + nr * 64 + pcol) = (unsigned)l0 | ((unsigned)l1 << 16);
    }
  }
  __syncthreads();
  unsigned short* Th = (unsigned short*)(out + ((long long)(b * 512 + 256)) * 4096);
  unsigned short* Tl = Th + 4096 * 256;
  #pragma unroll
  for (int q = 0; q < 2; q++) {
    int s = q * 256 + t;
    int n = s >> 3, sc = s & 7;
    int psc = sc ^ (n & 7);
    uint4 vh = *(const uint4*)(th + n * 64 + psc * 8);
    uint4 vl = *(const uint4*)(tl + n * 64 + psc * 8);
    *(uint4*)(Th + (long long)(n0 + n) * 256 + c0 + sc * 8) = vh;
    *(uint4*)(Tl + (long long)(n0 + n) * 256 + c0 + sc * 8) = vl;
  }
}

// K6 (last): x_preact = silu(x + pab) fp32 -> out[:,0:256]
__global__ __launch_bounds__(256) void k_act(
    const float* __restrict__ x, const float* __restrict__ pab,
    float* __restrict__ out) {
  long long e = ((long long)blockIdx.x * 256 + threadIdx.x) * 4;
  int b = (int)(e >> 20);
  int c = ((int)(e >> 12)) & 255;
  int n = (int)(e & 4095);
  float4 xv = *(const float4*)(x + e);
  float pa = pab[c];
  float4 o = {silu_f(xv.x + pa), silu_f(xv.y + pa), silu_f(xv.z + pa), silu_f(xv.w + pa)};
  *(float4*)(out + ((long long)(b * 512 + c)) * 4096 + n) = o;
}

// K2/K4: GEMM qkv rows [o_base, o_base+obt*128). USE_LO=1 -> 3-term split-bf16.
// 2-phase double-buffered pipeline, BK=32: issue next-tile global_load_lds, then
// ds_read+MFMA current tile, then ONE barrier (vmcnt drain overlaps MFMA cluster).
// Source-side XOR swizzle (chunk ^ ((row>>1)&3), 16B chunks) mirrored on reads.
//   part 0 (q): +bias+PE, FiLM -> out[:,0:256] packed (hi|lo<<16) u32
//   part 1 (k): +bias+PE      -> kv packed u32
//   part 2 (v): +bias         -> kv fp32
template <int USE_LO>
__global__ __launch_bounds__(256) void k_qkv(
    const unsigned short* __restrict__ Wh, const unsigned short* __restrict__ Wl,
    const float* __restrict__ qkvb,
    const float* __restrict__ peqh, const float* __restrict__ peqw,
    const float* __restrict__ pekh, const float* __restrict__ pekw,
    const float* __restrict__ modm, const float* __restrict__ modb,
    float* __restrict__ out, float* __restrict__ kv,
    int o_base, int obt) {
  extern __shared__ unsigned short sm[];
  const int BUFS = USE_LO ? 16384 : 8192;  // u16 per buffer

  int bx = blockIdx.x;
  int nb = bx & 31;
  int hb = bx >> 5;
  int ob = hb % obt;
  int b = hb / obt;
  int o0 = o_base + ob * 128, n0 = nb * 128;
  int t = threadIdx.x;
  int lane = t & 63, w = t >> 6;
  int wm = w >> 1, wn = w & 1;
  int l15 = lane & 15, l4 = lane >> 4;

  const unsigned short* Th =
      (const unsigned short*)(out + ((long long)(b * 512 + 256)) * 4096);
  const unsigned short* Tl = Th + 4096 * 256;

  // per-wave staging plane assignment (one plane / half-plane per wave)
  const unsigned short* src;
  int dstoff, row0;
  if (USE_LO) {
    if (w == 0)      { src = Wh; dstoff = 0;     row0 = o0; }
    else if (w == 1) { src = Wl; dstoff = 4096;  row0 = o0; }
    else if (w == 2) { src = Th; dstoff = 8192;  row0 = n0; }
    else             { src = Tl; dstoff = 12288; row0 = n0; }
  } else {
    if (w == 0)      { src = Wh; dstoff = 0;     row0 = o0; }
    else if (w == 1) { src = Wh; dstoff = 2048;  row0 = o0 + 64; }
    else if (w == 2) { src = Th; dstoff = 4096;  row0 = n0; }
    else             { src = Th; dstoff = 6144;  row0 = n0 + 64; }
  }
  const int nI = USE_LO ? 8 : 4;  // gload16 instrs per wave per K-step (1KB each)
  // source-side swizzle: lane writes LDS (row=l>>2, chunk=l&3); fetch logical
  // chunk (l&3) ^ ((l>>3)&3) so physical chunk = logical ^ ((row>>1)&3).
  int laneoff = (lane >> 2) * 256 + (((lane & 3) ^ ((lane >> 3) & 3)) << 3);
  const unsigned short* sbase = src + (long long)row0 * 256 + laneoff;

  f32x4 z = {0.f, 0.f, 0.f, 0.f};
  f32x4 acc[4][4];
  #pragma unroll
  for (int i = 0; i < 4; i++)
    #pragma unroll
    for (int j = 0; j < 4; j++) acc[i][j] = z;

  // read-side physical chunk for this lane (row%16 == l15, i*16 keeps (row>>1)&3)
  int sw = (l4 ^ ((l15 >> 1) & 3)) << 3;

  // prologue: stage K-step 0 into buf 0
  #pragma unroll
  for (int i = 0; i < nI; i++) gload16(sbase + i * 4096, sm + dstoff + i * 512);
  __syncthreads();

  int cur = 0;
  for (int step = 0; step < 8; ++step) {
    // issue next K-step's staging into the other buffer (stays in flight
    // across the MFMA cluster; drains at this iteration's barrier)
    if (step < 7) {
      const unsigned short* sp = sbase + (step + 1) * 32;
      unsigned short* dp = sm + (cur ^ 1) * BUFS + dstoff;
      #pragma unroll
      for (int i = 0; i < nI; i++) gload16(sp + i * 4096, dp + i * 512);
    }
    unsigned short* Ah = sm + cur * BUFS;
    unsigned short* Al = Ah + 4096;
    unsigned short* Bh = Ah + (USE_LO ? 8192 : 4096);
    unsigned short* Bl = Ah + 12288;
    bf16x8 ah[4], bh[4], al[4], bl[4];
    #pragma unroll
    for (int i = 0; i < 4; i++) {
      int rowA = (wm * 64 + i * 16 + l15) * 32;
      int rowB = (wn * 64 + i * 16 + l15) * 32;
      ah[i] = *(const bf16x8*)(Ah + rowA + sw);
      bh[i] = *(const bf16x8*)(Bh + rowB + sw);
      if (USE_LO) {
        al[i] = *(const bf16x8*)(Al + rowA + sw);
        bl[i] = *(const bf16x8*)(Bl + rowB + sw);
      }
    }
    #pragma unroll
    for (int i = 0; i < 4; i++)
      #pragma unroll
      for (int j = 0; j < 4; j++) {
        acc[i][j] = __builtin_amdgcn_mfma_f32_16x16x32_bf16(ah[i], bh[j], acc[i][j], 0, 0, 0);
        if (USE_LO) {
          acc[i][j] = __builtin_amdgcn_mfma_f32_16x16x32_bf16(ah[i], bl[j], acc[i][j], 0, 0, 0);
          acc[i][j] = __builtin_amdgcn_mfma_f32_16x16x32_bf16(al[i], bh[j], acc[i][j], 0, 0, 0);
        }
      }
    __syncthreads();
    cur ^= 1;
  }

  int part = o0 >> 8;
  #pragma unroll
  for (int i = 0; i < 4; i++) {
    #pragma unroll
    for (int r = 0; r < 4; r++) {
      int o = o0 + wm * 64 + i * 16 + l4 * 4 + r;
      int cch = o & 255;
      float bias = qkvb[o];
      float mm = 0.f, mb = 0.f;
      if (part == 0) { mm = modm[b * 256 + cch]; mb = modb[b * 256 + cch]; }
      #pragma unroll
      for (int j = 0; j < 4; j++) {
        int n = n0 + wn * 64 + j * 16 + l15;
        float v = acc[i][j][r] + bias;
        int hh = n >> 6, ww = n & 63;
        if (part == 0) {
          v += peqh[cch * 64 + hh] + peqw[cch * 64 + ww];
          v = v * mm + mb;
          unsigned short h, l; split2(v, h, l);
          ((unsigned*)out)[((long long)(b * 512 + cch)) * 4096 + n] =
              (unsigned)h | ((unsigned)l << 16);
        } else if (part == 1) {
          v += pekh[cch * 64 + hh] + pekw[cch * 64 + ww];
          unsigned short h, l; split2(v, h, l);
          ((unsigned*)kv)[((long long)(b * 256 + cch)) * 4096 + n] =
              (unsigned)h | ((unsigned)l << 16);
        } else {
          kv[((long long)(b * 256 + cch)) * 4096 + n] = v;
        }
      }
    }
  }
}

// K3: logitsP[chunk][b,h,c,d] = scale * sum_{n in chunk} q[c,n] k[d,n]
// q, k read as packed split-bf16 (written by k_qkv) -> v_perm unpack, no cvt.
__global__ __launch_bounds__(256) void k_logits(
    const unsigned* __restrict__ qp, const unsigned* __restrict__ kp,
    float* __restrict__ logitsP) {
  int bx = blockIdx.x;
  int chunk = bx & 3, bh = bx >> 2;
  int b = bh >> 3, h = bh & 7;
  int t = threadIdx.x, lane = t & 63, w = t >> 6;
  int l15 = lane & 15, l4 = lane >> 4;
  const unsigned* qb = qp + ((long long)(b * 512 + h * 32)) * 4096;
  const unsigned* kb = kp + ((long long)(b * 256 + h * 32)) * 4096;
  f32x4 z = {0.f, 0.f, 0.f, 0.f};
  f32x4 acc[2][2] = {z, z, z, z};
  int nstep0 = chunk * 1024 + w * 256;
  for (int it = 0; it < 8; it++) {
    int n = nstep0 + it * 32 + l4 * 8;
    bf16x8 qh0, ql0, qh1, ql1, kh0, kl0, kh1, kl1;
    unpack8(qb + (long long)l15 * 4096 + n, qh0, ql0);
    unpack8(qb + (long long)(16 + l15) * 4096 + n, qh1, ql1);
    unpack8(kb + (long long)l15 * 4096 + n, kh0, kl0);
    unpack8(kb + (long long)(16 + l15) * 4096 + n, kh1, kl1);
    acc[0][0] = __builtin_amdgcn_mfma_f32_16x16x32_bf16(qh0, kh0, acc[0][0], 0, 0, 0);
    acc[0][0] = __builtin_amdgcn_mfma_f32_16x16x32_bf16(qh0, kl0, acc[0][0], 0, 0, 0);
    acc[0][0] = __builtin_amdgcn_mfma_f32_16x16x32_bf16(ql0, kh0, acc[0][0], 0, 0, 0);
    acc[0][1] = __builtin_amdgcn_mfma_f32_16x16x32_bf16(qh0, kh1, acc[0][1], 0, 0, 0);
    acc[0][1] = __builtin_amdgcn_mfma_f32_16x16x32_bf16(qh0, kl1, acc[0][1], 0, 0, 0);
    acc[0][1] = __builtin_amdgcn_mfma_f32_16x16x32_bf16(ql0, kh1, acc[0][1], 0, 0, 0);
    acc[1][0] = __builtin_amdgcn_mfma_f32_16x16x32_bf16(qh1, kh0, acc[1][0], 0, 0, 0);
    acc[1][0] = __builtin_amdgcn_mfma_f32_16x16x32_bf16(qh1, kl0, acc[1][0], 0, 0, 0);
    acc[1][0] = __builtin_amdgcn_mfma_f32_16x16x32_bf16(ql1, kh0, acc[1][0], 0, 0, 0);
    acc[1][1] = __builtin_amdgcn_mfma_f32_16x16x32_bf16(qh1, kh1, acc[1][1], 0, 0, 0);
    acc[1][1] = __builtin_amdgcn_mfma_f32_16x16x32_bf16(qh1, kl1, acc[1][1], 0, 0, 0);
    acc[1][1] = __builtin_amdgcn_mfma_f32_16x16x32_bf16(ql1, kh1, acc[1][1], 0, 0, 0);
  }
  __shared__ float red[4][1024];
  #pragma unroll
  for (int ch = 0; ch < 2; ch++)
    #pragma unroll
    for (int dh = 0; dh < 2; dh++)
      #pragma unroll
      for (int r = 0; r < 4; r++) {
        int crow = ch * 16 + l4 * 4 + r;
        int dcol = dh * 16 + l15;
        red[w][crow * 32 + dcol] = acc[ch][dh][r];
      }
  __syncthreads();
  const float scale = 0.1767766952966369f;  // 1/sqrt(32)
  #pragma unroll
  for (int i = 0; i < 4; i++) {
    int idx = i * 256 + t;
    float s = (red[0][idx] + red[1][idx] + red[2][idx] + red[3][idx]) * scale;
    logitsP[(long long)chunk * 131072 + bh * 1024 + idx] = s;
  }
}

// K5: softmax (sum 4 partials) + out = weights @ v -> out[:,256:512] fp32
__global__ __launch_bounds__(256) void k_pv(
    const float* __restrict__ kv,    // v
    const float* __restrict__ logitsP,
    float* __restrict__ out) {
  int bx = blockIdx.x;
  int ntile = bx & 15, bh = bx >> 4;
  int b = bh >> 3, h = bh & 7;
  int t = threadIdx.x;
  __shared__ float raw[1024];
  __shared__ float wsm[32][33];
  #pragma unroll
  for (int i = 0; i < 4; i++) {
    int idx = i * 256 + t;
    raw[idx] = logitsP[bh * 1024 + idx] + logitsP[131072 + bh * 1024 + idx]
             + logitsP[262144 + bh * 1024 + idx] + logitsP[393216 + bh * 1024 + idx];
  }
  __syncthreads();
  if (t < 32) {
    float mx = -1e30f;
    for (int d = 0; d < 32; d++) mx = fmaxf(mx, raw[t * 32 + d]);
    float e[32]; float s = 0.f;
    for (int d = 0; d < 32; d++) { e[d] = __expf(raw[t * 32 + d] - mx); s += e[d]; }
    float inv = 1.0f / s;
    for (int d = 0; d < 32; d++) wsm[t][d] = e[d] * inv;
  }
  __syncthreads();
  int rg = t >> 6;          // wave-uniform -> wsm broadcast
  int nl = (t & 63) * 4;
  int n0 = ntile * 256 + nl;
  const float* vb = kv + ((long long)(b * 256 + h * 32)) * 4096 + n0;
  float acc[8][4];
  #pragma unroll
  for (int r = 0; r < 8; r++)
    #pragma unroll
    for (int i = 0; i < 4; i++) acc[r][i] = 0.f;
  for (int d = 0; d < 32; d++) {
    float4 vv = *(const float4*)(vb + (long long)d * 4096);
    #pragma unroll
    for (int r = 0; r < 8; r++) {
      float wv = wsm[rg * 8 + r][d];
      acc[r][0] += wv * vv.x; acc[r][1] += wv * vv.y;
      acc[r][2] += wv * vv.z; acc[r][3] += wv * vv.w;
    }
  }
  #pragma unroll
  for (int r = 0; r < 8; r++) {
    long long oidx = ((long long)(b * 512 + 256 + h * 32 + rg * 8 + r)) * 4096 + n0;
    float4 ov = {acc[r][0], acc[r][1], acc[r][2], acc[r][3]};
    *(float4*)(out + oidx) = ov;
  }
}

extern "C" void kernel_launch(void* const* d_in, const int* in_sizes, int n_in,
                              void* d_out, int out_size, void* d_ws, size_t ws_size,
                              hipStream_t stream) {
  const float* x    = (const float*)d_in[0];
  const float* modm = (const float*)d_in[1];
  const float* modb = (const float*)d_in[2];
  const float* Wq   = (const float*)d_in[3];
  const float* qkvb = (const float*)d_in[4];
  const float* peqh = (const float*)d_in[5];
  const float* peqw = (const float*)d_in[6];
  const float* pekh = (const float*)d_in[7];
  const float* pekw = (const float*)d_in[8];
  const float* pab  = (const float*)d_in[9];
  const float* pqb  = (const float*)d_in[10];
  float* out = (float*)d_out;

  // ws layout (67 MB total, <= 69.2 MB proven):
  //   [0, 0.75MB)  Wh/Wl u16[768][256] split-bf16 planes
  //   [1MB, 3MB)   logitsP f32[4][128][1024]
  //   [3MB, 67MB)  kv: k packed u32 [16][256][4096], then v fp32 (same region)
  unsigned short* Wh = (unsigned short*)d_ws;
  unsigned short* Wl = Wh + 768 * 256;
  float* logitsP = (float*)((char*)d_ws + (1 << 20));
  float* kv = (float*)((char*)d_ws + 3 * (1 << 20));

  k_wsplit<<<96, 256, 0, stream>>>(Wq, Wh, Wl);
  k_prep<<<4096, 256, 0, stream>>>(x, pab, pqb, out);
  k_qkv<1><<<2048, 256, 65536, stream>>>(Wh, Wl, qkvb, peqh, peqw, pekh, pekw,
                                         modm, modb, out, kv, 0, 4);
  k_logits<<<512, 256, 0, stream>>>((const unsigned*)out, (const unsigned*)kv, logitsP);
  k_qkv<0><<<1024, 256, 32768, stream>>>(Wh, Wl, qkvb, peqh, peqw, pekh, pekw,
                                         modm, modb, out, kv, 512, 2);
  k_pv<<<2048, 256, 0, stream>>>(kv, logitsP, out);
  k_act<<<16384, 256, 0, stream>>>(x, pab, out);
}

// Round 3
// 405.764 us; speedup vs baseline: 1.2079x; 1.0073x over previous
//
#include <hip/hip_runtime.h>

typedef short bf16x8 __attribute__((ext_vector_type(8)));
typedef float f32x4 __attribute__((ext_vector_type(4)));

__device__ __forceinline__ float b2f(unsigned short u) {
  union { unsigned int i; float f; } v; v.i = ((unsigned int)u) << 16; return v.f;
}
__device__ __forceinline__ unsigned short f2b(float f) {
  unsigned int u = __float_as_uint(f);
  u += 0x7fffu + ((u >> 16) & 1u);
  return (unsigned short)(u >> 16);
}
__device__ __forceinline__ float silu_f(float s) { return s / (1.0f + __expf(-s)); }

// split fp32 -> (hi, lo) bf16
__device__ __forceinline__ void split2(float f, unsigned short& h, unsigned short& l) {
  h = f2b(f);
  l = f2b(f - b2f(h));
}

// async 16B/lane global->LDS. LDS dest = wave-uniform base + lane*16 (linear).
__device__ __forceinline__ void gload16(const unsigned short* g, unsigned short* l) {
  __builtin_amdgcn_global_load_lds(
      (const __attribute__((address_space(1))) unsigned int*)g,
      (__attribute__((address_space(3))) unsigned int*)l, 16, 0, 0);
}

// unpack 8 packed (hi | lo<<16) u32 -> hi/lo bf16x8 via v_perm (2 ops per pair)
__device__ __forceinline__ void unpack8(const unsigned* p, bf16x8& hi, bf16x8& lo) {
  uint4 a = *(const uint4*)p;
  uint4 b = *(const uint4*)(p + 4);
  unsigned u[8] = {a.x, a.y, a.z, a.w, b.x, b.y, b.z, b.w};
  unsigned hw[4], lw[4];
  #pragma unroll
  for (int j = 0; j < 4; j++) {
    hw[j] = __builtin_amdgcn_perm(u[2 * j + 1], u[2 * j], 0x05040100u);
    lw[j] = __builtin_amdgcn_perm(u[2 * j + 1], u[2 * j], 0x07060302u);
  }
  hi = *(bf16x8*)hw;
  lo = *(bf16x8*)lw;
}

// K0: split W fp32 -> Wh/Wl bf16 planes [768][256], once.
__global__ __launch_bounds__(256) void k_wsplit(
    const float* __restrict__ W, unsigned short* __restrict__ Wh,
    unsigned short* __restrict__ Wl) {
  int e = (blockIdx.x * 256 + threadIdx.x) * 8;  // 96 blocks * 256 * 8 = 768*256
  float4 a = *(const float4*)(W + e);
  float4 b = *(const float4*)(W + e + 4);
  float v[8] = {a.x, a.y, a.z, a.w, b.x, b.y, b.z, b.w};
  unsigned short h[8], l[8];
  #pragma unroll
  for (int j = 0; j < 8; j++) split2(v[j], h[j], l[j]);
  uint4 ph, pl;
  ph.x = h[0] | ((unsigned)h[1] << 16); ph.y = h[2] | ((unsigned)h[3] << 16);
  ph.z = h[4] | ((unsigned)h[5] << 16); ph.w = h[6] | ((unsigned)h[7] << 16);
  pl.x = l[0] | ((unsigned)l[1] << 16); pl.y = l[2] | ((unsigned)l[3] << 16);
  pl.z = l[4] | ((unsigned)l[5] << 16); pl.w = l[6] | ((unsigned)l[7] << 16);
  *(uint4*)(Wh + e) = ph;
  *(uint4*)(Wl + e) = pl;
}

// K1: T = silu(x + pab) + pqb, written TRANSPOSED as split planes into out[:,256:512]:
//   per batch: Th u16[4096][256] then Tl u16[4096][256] (2MB + 2MB = exactly the region).
__global__ __launch_bounds__(256) void k_prep(
    const float* __restrict__ x, const float* __restrict__ pab,
    const float* __restrict__ pqb, float* __restrict__ out) {
  __shared__ unsigned short th[64 * 64], tl[64 * 64];  // [n][c], sub-chunk swizzled
  int blk = blockIdx.x;
  int nb = blk & 63;
  int cb = (blk >> 6) & 3;
  int b = blk >> 8;
  int n0 = nb * 64, c0 = cb * 64;
  int t = threadIdx.x;
  int nn = (t & 15) * 4;
  #pragma unroll
  for (int p = 0; p < 2; p++) {
    int c = 2 * (p * 16 + (t >> 4));  // even
    float pa0 = pab[c0 + c], pq0 = pqb[c0 + c];
    float pa1 = pab[c0 + c + 1], pq1 = pqb[c0 + c + 1];
    float4 x0 = *(const float4*)(x + ((long long)(b * 256 + c0 + c)) * 4096 + n0 + nn);
    float4 x1 = *(const float4*)(x + ((long long)(b * 256 + c0 + c + 1)) * 4096 + n0 + nn);
    float t0[4] = {silu_f(x0.x + pa0) + pq0, silu_f(x0.y + pa0) + pq0,
                   silu_f(x0.z + pa0) + pq0, silu_f(x0.w + pa0) + pq0};
    float t1[4] = {silu_f(x1.x + pa1) + pq1, silu_f(x1.y + pa1) + pq1,
                   silu_f(x1.z + pa1) + pq1, silu_f(x1.w + pa1) + pq1};
    #pragma unroll
    for (int j = 0; j < 4; j++) {
      int nr = nn + j;
      unsigned short h0, l0, h1, l1;
      split2(t0[j], h0, l0);
      split2(t1[j], h1, l1);
      // physical col: swizzle 8-elem sub-chunk by row (c even => pair stays in chunk)
      int pcol = ((((c >> 3) ^ (nr & 7)) << 3) | (c & 7));
      *(unsigned int*)(th + nr * 64 + pcol) = (unsigned)h0 | ((unsigned)h1 << 16);
      *(unsigned int*)(tl + nr * 64 + pcol) = (unsigned)l0 | ((unsigned)l1 << 16);
    }
  }
  __syncthreads();
  unsigned short* Th = (unsigned short*)(out + ((long long)(b * 512 + 256)) * 4096);
  unsigned short* Tl = Th + 4096 * 256;
  #pragma unroll
  for (int q = 0; q < 2; q++) {
    int s = q * 256 + t;
    int n = s >> 3, sc = s & 7;
    int psc = sc ^ (n & 7);
    uint4 vh = *(const uint4*)(th + n * 64 + psc * 8);
    uint4 vl = *(const uint4*)(tl + n * 64 + psc * 8);
    *(uint4*)(Th + (long long)(n0 + n) * 256 + c0 + sc * 8) = vh;
    *(uint4*)(Tl + (long long)(n0 + n) * 256 + c0 + sc * 8) = vl;
  }
}

// K6 (last): x_preact = silu(x + pab) fp32 -> out[:,0:256]
__global__ __launch_bounds__(256) void k_act(
    const float* __restrict__ x, const float* __restrict__ pab,
    float* __restrict__ out) {
  long long e = ((long long)blockIdx.x * 256 + threadIdx.x) * 4;
  int b = (int)(e >> 20);
  int c = ((int)(e >> 12)) & 255;
  int n = (int)(e & 4095);
  float4 xv = *(const float4*)(x + e);
  float pa = pab[c];
  float4 o = {silu_f(xv.x + pa), silu_f(xv.y + pa), silu_f(xv.z + pa), silu_f(xv.w + pa)};
  *(float4*)(out + ((long long)(b * 512 + c)) * 4096 + n) = o;
}

// K2/K4: GEMM qkv rows [o_base, o_base+obt*128). USE_LO=1 -> 3-term split-bf16.
// 2-phase double-buffered pipeline, BK=32, COUNTED vmcnt (T4): prefetch issued
// at step top stays in flight across the barrier; wait only for the previous
// batch (vmcnt(nI)), never drain to 0 in the main loop. Raw s_barrier (no
// implicit vmcnt(0) drain). Source-side XOR swizzle mirrored on reads.
//   part 0 (q): +bias+PE, FiLM -> out[:,0:256] packed (hi|lo<<16) u32
//   part 1 (k): +bias+PE      -> kv packed u32
//   part 2 (v): +bias         -> kv fp32
template <int USE_LO>
__global__ __launch_bounds__(256) void k_qkv(
    const unsigned short* __restrict__ Wh, const unsigned short* __restrict__ Wl,
    const float* __restrict__ qkvb,
    const float* __restrict__ peqh, const float* __restrict__ peqw,
    const float* __restrict__ pekh, const float* __restrict__ pekw,
    const float* __restrict__ modm, const float* __restrict__ modb,
    float* __restrict__ out, float* __restrict__ kv,
    int o_base, int obt) {
  extern __shared__ unsigned short sm[];
  const int BUFS = USE_LO ? 16384 : 8192;  // u16 per buffer

  int bx = blockIdx.x;
  int nb = bx & 31;
  int hb = bx >> 5;
  int ob = hb % obt;
  int b = hb / obt;
  int o0 = o_base + ob * 128, n0 = nb * 128;
  int t = threadIdx.x;
  int lane = t & 63, w = t >> 6;
  int wm = w >> 1, wn = w & 1;
  int l15 = lane & 15, l4 = lane >> 4;

  const unsigned short* Th =
      (const unsigned short*)(out + ((long long)(b * 512 + 256)) * 4096);
  const unsigned short* Tl = Th + 4096 * 256;

  // per-wave staging plane assignment (one plane / half-plane per wave)
  const unsigned short* src;
  int dstoff, row0;
  if (USE_LO) {
    if (w == 0)      { src = Wh; dstoff = 0;     row0 = o0; }
    else if (w == 1) { src = Wl; dstoff = 4096;  row0 = o0; }
    else if (w == 2) { src = Th; dstoff = 8192;  row0 = n0; }
    else             { src = Tl; dstoff = 12288; row0 = n0; }
  } else {
    if (w == 0)      { src = Wh; dstoff = 0;     row0 = o0; }
    else if (w == 1) { src = Wh; dstoff = 2048;  row0 = o0 + 64; }
    else if (w == 2) { src = Th; dstoff = 4096;  row0 = n0; }
    else             { src = Th; dstoff = 6144;  row0 = n0 + 64; }
  }
  const int nI = USE_LO ? 8 : 4;  // gload16 instrs per wave per K-step (1KB each)
  // source-side swizzle: lane writes LDS (row=l>>2, chunk=l&3); fetch logical
  // chunk (l&3) ^ ((l>>3)&3) so physical chunk = logical ^ ((row>>1)&3).
  int laneoff = (lane >> 2) * 256 + (((lane & 3) ^ ((lane >> 3) & 3)) << 3);
  const unsigned short* sbase = src + (long long)row0 * 256 + laneoff;

  f32x4 z = {0.f, 0.f, 0.f, 0.f};
  f32x4 acc[4][4];
  #pragma unroll
  for (int i = 0; i < 4; i++)
    #pragma unroll
    for (int j = 0; j < 4; j++) acc[i][j] = z;

  // read-side physical chunk for this lane (row%16 == l15, i*16 keeps (row>>1)&3)
  int sw = (l4 ^ ((l15 >> 1) & 3)) << 3;

  // prologue: stage K-step 0 into buf 0 (stays in flight; counted below)
  #pragma unroll
  for (int i = 0; i < nI; i++) gload16(sbase + i * 4096, sm + dstoff + i * 512);

  int cur = 0;
  for (int step = 0; step < 8; ++step) {
    // issue next K-step's prefetch; wait COUNTED vmcnt: previous batch done,
    // just-issued batch stays in flight across the barrier + MFMA cluster.
    if (step < 7) {
      const unsigned short* sp = sbase + (step + 1) * 32;
      unsigned short* dp = sm + (cur ^ 1) * BUFS + dstoff;
      #pragma unroll
      for (int i = 0; i < nI; i++) gload16(sp + i * 4096, dp + i * 512);
      if (USE_LO) asm volatile("s_waitcnt vmcnt(8)" ::: "memory");
      else        asm volatile("s_waitcnt vmcnt(4)" ::: "memory");
    } else {
      asm volatile("s_waitcnt vmcnt(0)" ::: "memory");
    }
    __builtin_amdgcn_s_barrier();          // everyone's tile-step data in LDS
    __builtin_amdgcn_sched_barrier(0);     // pin ds_reads below the barrier
    unsigned short* Ah = sm + cur * BUFS;
    unsigned short* Al = Ah + 4096;
    unsigned short* Bh = Ah + (USE_LO ? 8192 : 4096);
    unsigned short* Bl = Ah + 12288;
    bf16x8 ah[4], bh[4], al[4], bl[4];
    #pragma unroll
    for (int i = 0; i < 4; i++) {
      int rowA = (wm * 64 + i * 16 + l15) * 32;
      int rowB = (wn * 64 + i * 16 + l15) * 32;
      ah[i] = *(const bf16x8*)(Ah + rowA + sw);
      bh[i] = *(const bf16x8*)(Bh + rowB + sw);
      if (USE_LO) {
        al[i] = *(const bf16x8*)(Al + rowA + sw);
        bl[i] = *(const bf16x8*)(Bl + rowB + sw);
      }
    }
    #pragma unroll
    for (int i = 0; i < 4; i++)
      #pragma unroll
      for (int j = 0; j < 4; j++) {
        acc[i][j] = __builtin_amdgcn_mfma_f32_16x16x32_bf16(ah[i], bh[j], acc[i][j], 0, 0, 0);
        if (USE_LO) {
          acc[i][j] = __builtin_amdgcn_mfma_f32_16x16x32_bf16(ah[i], bl[j], acc[i][j], 0, 0, 0);
          acc[i][j] = __builtin_amdgcn_mfma_f32_16x16x32_bf16(al[i], bh[j], acc[i][j], 0, 0, 0);
        }
      }
    __builtin_amdgcn_sched_barrier(0);
    // reads of buf `cur` done (consumed by MFMA); allow next prefetch to
    // overwrite buf cur^1 ... bare barrier, NO vmcnt drain.
    __builtin_amdgcn_s_barrier();
    cur ^= 1;
  }

  int part = o0 >> 8;
  #pragma unroll
  for (int i = 0; i < 4; i++) {
    #pragma unroll
    for (int r = 0; r < 4; r++) {
      int o = o0 + wm * 64 + i * 16 + l4 * 4 + r;
      int cch = o & 255;
      float bias = qkvb[o];
      float mm = 0.f, mb = 0.f;
      if (part == 0) { mm = modm[b * 256 + cch]; mb = modb[b * 256 + cch]; }
      #pragma unroll
      for (int j = 0; j < 4; j++) {
        int n = n0 + wn * 64 + j * 16 + l15;
        float v = acc[i][j][r] + bias;
        int hh = n >> 6, ww = n & 63;
        if (part == 0) {
          v += peqh[cch * 64 + hh] + peqw[cch * 64 + ww];
          v = v * mm + mb;
          unsigned short h, l; split2(v, h, l);
          ((unsigned*)out)[((long long)(b * 512 + cch)) * 4096 + n] =
              (unsigned)h | ((unsigned)l << 16);
        } else if (part == 1) {
          v += pekh[cch * 64 + hh] + pekw[cch * 64 + ww];
          unsigned short h, l; split2(v, h, l);
          ((unsigned*)kv)[((long long)(b * 256 + cch)) * 4096 + n] =
              (unsigned)h | ((unsigned)l << 16);
        } else {
          kv[((long long)(b * 256 + cch)) * 4096 + n] = v;
        }
      }
    }
  }
}

// K3: logitsP[chunk][b,h,c,d] = scale * sum_{n in chunk} q[c,n] k[d,n]
// q, k read as packed split-bf16 (written by k_qkv) -> v_perm unpack, no cvt.
__global__ __launch_bounds__(256) void k_logits(
    const unsigned* __restrict__ qp, const unsigned* __restrict__ kp,
    float* __restrict__ logitsP) {
  int bx = blockIdx.x;
  int chunk = bx & 3, bh = bx >> 2;
  int b = bh >> 3, h = bh & 7;
  int t = threadIdx.x, lane = t & 63, w = t >> 6;
  int l15 = lane & 15, l4 = lane >> 4;
  const unsigned* qb = qp + ((long long)(b * 512 + h * 32)) * 4096;
  const unsigned* kb = kp + ((long long)(b * 256 + h * 32)) * 4096;
  f32x4 z = {0.f, 0.f, 0.f, 0.f};
  f32x4 acc[2][2] = {z, z, z, z};
  int nstep0 = chunk * 1024 + w * 256;
  for (int it = 0; it < 8; it++) {
    int n = nstep0 + it * 32 + l4 * 8;
    bf16x8 qh0, ql0, qh1, ql1, kh0, kl0, kh1, kl1;
    unpack8(qb + (long long)l15 * 4096 + n, qh0, ql0);
    unpack8(qb + (long long)(16 + l15) * 4096 + n, qh1, ql1);
    unpack8(kb + (long long)l15 * 4096 + n, kh0, kl0);
    unpack8(kb + (long long)(16 + l15) * 4096 + n, kh1, kl1);
    acc[0][0] = __builtin_amdgcn_mfma_f32_16x16x32_bf16(qh0, kh0, acc[0][0], 0, 0, 0);
    acc[0][0] = __builtin_amdgcn_mfma_f32_16x16x32_bf16(qh0, kl0, acc[0][0], 0, 0, 0);
    acc[0][0] = __builtin_amdgcn_mfma_f32_16x16x32_bf16(ql0, kh0, acc[0][0], 0, 0, 0);
    acc[0][1] = __builtin_amdgcn_mfma_f32_16x16x32_bf16(qh0, kh1, acc[0][1], 0, 0, 0);
    acc[0][1] = __builtin_amdgcn_mfma_f32_16x16x32_bf16(qh0, kl1, acc[0][1], 0, 0, 0);
    acc[0][1] = __builtin_amdgcn_mfma_f32_16x16x32_bf16(ql0, kh1, acc[0][1], 0, 0, 0);
    acc[1][0] = __builtin_amdgcn_mfma_f32_16x16x32_bf16(qh1, kh0, acc[1][0], 0, 0, 0);
    acc[1][0] = __builtin_amdgcn_mfma_f32_16x16x32_bf16(qh1, kl0, acc[1][0], 0, 0, 0);
    acc[1][0] = __builtin_amdgcn_mfma_f32_16x16x32_bf16(ql1, kh0, acc[1][0], 0, 0, 0);
    acc[1][1] = __builtin_amdgcn_mfma_f32_16x16x32_bf16(qh1, kh1, acc[1][1], 0, 0, 0);
    acc[1][1] = __builtin_amdgcn_mfma_f32_16x16x32_bf16(qh1, kl1, acc[1][1], 0, 0, 0);
    acc[1][1] = __builtin_amdgcn_mfma_f32_16x16x32_bf16(ql1, kh1, acc[1][1], 0, 0, 0);
  }
  __shared__ float red[4][1024];
  #pragma unroll
  for (int ch = 0; ch < 2; ch++)
    #pragma unroll
    for (int dh = 0; dh < 2; dh++)
      #pragma unroll
      for (int r = 0; r < 4; r++) {
        int crow = ch * 16 + l4 * 4 + r;
        int dcol = dh * 16 + l15;
        red[w][crow * 32 + dcol] = acc[ch][dh][r];
      }
  __syncthreads();
  const float scale = 0.1767766952966369f;  // 1/sqrt(32)
  #pragma unroll
  for (int i = 0; i < 4; i++) {
    int idx = i * 256 + t;
    float s = (red[0][idx] + red[1][idx] + red[2][idx] + red[3][idx]) * scale;
    logitsP[(long long)chunk * 131072 + bh * 1024 + idx] = s;
  }
}

// K5: softmax (sum 4 partials) + out = weights @ v -> out[:,256:512] fp32
__global__ __launch_bounds__(256) void k_pv(
    const float* __restrict__ kv,    // v
    const float* __restrict__ logitsP,
    float* __restrict__ out) {
  int bx = blockIdx.x;
  int ntile = bx & 15, bh = bx >> 4;
  int b = bh >> 3, h = bh & 7;
  int t = threadIdx.x;
  __shared__ float raw[1024];
  __shared__ float wsm[32][33];
  #pragma unroll
  for (int i = 0; i < 4; i++) {
    int idx = i * 256 + t;
    raw[idx] = logitsP[bh * 1024 + idx] + logitsP[131072 + bh * 1024 + idx]
             + logitsP[262144 + bh * 1024 + idx] + logitsP[393216 + bh * 1024 + idx];
  }
  __syncthreads();
  if (t < 32) {
    float mx = -1e30f;
    for (int d = 0; d < 32; d++) mx = fmaxf(mx, raw[t * 32 + d]);
    float e[32]; float s = 0.f;
    for (int d = 0; d < 32; d++) { e[d] = __expf(raw[t * 32 + d] - mx); s += e[d]; }
    float inv = 1.0f / s;
    for (int d = 0; d < 32; d++) wsm[t][d] = e[d] * inv;
  }
  __syncthreads();
  int rg = t >> 6;          // wave-uniform -> wsm broadcast
  int nl = (t & 63) * 4;
  int n0 = ntile * 256 + nl;
  const float* vb = kv + ((long long)(b * 256 + h * 32)) * 4096 + n0;
  float acc[8][4];
  #pragma unroll
  for (int r = 0; r < 8; r++)
    #pragma unroll
    for (int i = 0; i < 4; i++) acc[r][i] = 0.f;
  for (int d = 0; d < 32; d++) {
    float4 vv = *(const float4*)(vb + (long long)d * 4096);
    #pragma unroll
    for (int r = 0; r < 8; r++) {
      float wv = wsm[rg * 8 + r][d];
      acc[r][0] += wv * vv.x; acc[r][1] += wv * vv.y;
      acc[r][2] += wv * vv.z; acc[r][3] += wv * vv.w;
    }
  }
  #pragma unroll
  for (int r = 0; r < 8; r++) {
    long long oidx = ((long long)(b * 512 + 256 + h * 32 + rg * 8 + r)) * 4096 + n0;
    float4 ov = {acc[r][0], acc[r][1], acc[r][2], acc[r][3]};
    *(float4*)(out + oidx) = ov;
  }
}

extern "C" void kernel_launch(void* const* d_in, const int* in_sizes, int n_in,
                              void* d_out, int out_size, void* d_ws, size_t ws_size,
                              hipStream_t stream) {
  const float* x    = (const float*)d_in[0];
  const float* modm = (const float*)d_in[1];
  const float* modb = (const float*)d_in[2];
  const float* Wq   = (const float*)d_in[3];
  const float* qkvb = (const float*)d_in[4];
  const float* peqh = (const float*)d_in[5];
  const float* peqw = (const float*)d_in[6];
  const float* pekh = (const float*)d_in[7];
  const float* pekw = (const float*)d_in[8];
  const float* pab  = (const float*)d_in[9];
  const float* pqb  = (const float*)d_in[10];
  float* out = (float*)d_out;

  // ws layout (67 MB total, <= 69.2 MB proven):
  //   [0, 0.75MB)  Wh/Wl u16[768][256] split-bf16 planes
  //   [1MB, 3MB)   logitsP f32[4][128][1024]
  //   [3MB, 67MB)  kv: k packed u32 [16][256][4096], then v fp32 (same region)
  unsigned short* Wh = (unsigned short*)d_ws;
  unsigned short* Wl = Wh + 768 * 256;
  float* logitsP = (float*)((char*)d_ws + (1 << 20));
  float* kv = (float*)((char*)d_ws + 3 * (1 << 20));

  k_wsplit<<<96, 256, 0, stream>>>(Wq, Wh, Wl);
  k_prep<<<4096, 256, 0, stream>>>(x, pab, pqb, out);
  k_qkv<1><<<2048, 256, 65536, stream>>>(Wh, Wl, qkvb, peqh, peqw, pekh, pekw,
                                         modm, modb, out, kv, 0, 4);
  k_logits<<<512, 256, 0, stream>>>((const unsigned*)out, (const unsigned*)kv, logitsP);
  k_qkv<0><<<1024, 256, 32768, stream>>>(Wh, Wl, qkvb, peqh, peqw, pekh, pekw,
                                         modm, modb, out, kv, 512, 2);
  k_pv<<<2048, 256, 0, stream>>>(kv, logitsP, out);
  k_act<<<16384, 256, 0, stream>>>(x, pab, out);
}